// Round 4
// baseline (1156.786 us; speedup 1.0000x reference)
//
#include <hip/hip_runtime.h>

typedef __bf16 bf16_t;
typedef __bf16 bf16x8 __attribute__((ext_vector_type(8)));
typedef float f32x4 __attribute__((ext_vector_type(4)));

#define MFMA16(a, b, c) __builtin_amdgcn_mfma_f32_16x16x32_bf16((a), (b), (c), 0, 0, 0)

__device__ __forceinline__ bf16_t f2b(float f) { return (bf16_t)f; }

__device__ __forceinline__ void gl_lds16(const void* g, void* l) {
    __builtin_amdgcn_global_load_lds(
        (const __attribute__((address_space(1))) void*)g,
        (__attribute__((address_space(3))) void*)l, 16, 0, 0);
}

// ---------------------------------------------------------------------------
// prep: W (1024x1024 f32, [c][n]) -> WT (bf16, [n][c]) for w_q,w_k,w_v,w_o
// ---------------------------------------------------------------------------
__global__ __launch_bounds__(256) void prep_kernel(
    const float* __restrict__ w0, const float* __restrict__ w1,
    const float* __restrict__ w2, const float* __restrict__ w3,
    bf16_t* __restrict__ WT)
{
    int z = blockIdx.z;
    const float* W = (z == 0) ? w0 : (z == 1) ? w1 : (z == 2) ? w2 : w3;
    bf16_t* dst = WT + ((size_t)z << 20);
    __shared__ float lds[64 * 65];
    int n0 = blockIdx.x * 64, c0 = blockIdx.y * 64;
    int t = threadIdx.x;
    int rl = t >> 2, q4 = t & 3;
    const float* src = W + (size_t)(c0 + rl) * 1024 + n0 + q4 * 16;
    float4 a0 = *(const float4*)(src);
    float4 a1 = *(const float4*)(src + 4);
    float4 a2 = *(const float4*)(src + 8);
    float4 a3 = *(const float4*)(src + 12);
    float* lr = lds + rl * 65 + q4 * 16;
    lr[0] = a0.x; lr[1] = a0.y; lr[2] = a0.z; lr[3] = a0.w;
    lr[4] = a1.x; lr[5] = a1.y; lr[6] = a1.z; lr[7] = a1.w;
    lr[8] = a2.x; lr[9] = a2.y; lr[10] = a2.z; lr[11] = a2.w;
    lr[12] = a3.x; lr[13] = a3.y; lr[14] = a3.z; lr[15] = a3.w;
    __syncthreads();
    bf16x8 o0, o1;
#pragma unroll
    for (int j = 0; j < 8; ++j) o0[j] = f2b(lds[(q4 * 16 + j) * 65 + rl]);
#pragma unroll
    for (int j = 0; j < 8; ++j) o1[j] = f2b(lds[(q4 * 16 + 8 + j) * 65 + rl]);
    bf16_t* dp = dst + (size_t)(n0 + rl) * 1024 + c0 + q4 * 16;
    *(bf16x8*)(dp) = o0;
    *(bf16x8*)(dp + 8) = o1;
}

// ---------------------------------------------------------------------------
// gemm (m97-style): C[8192][1024] = A[8192][1024] @ W (WT[n][c] bf16)
// BK=64, global_load_lds width-16 for A and B, source-pre-swizzled chunks.
// mode 0/1/2: A = q/k/v f32 (LDS tile stays f32, cvt at frag build)
// mode 3:     A = ctx bf16
// 128x128 tile, 256 threads (4 waves 2x2), each wave 64x64 out.
// ---------------------------------------------------------------------------
__global__ __launch_bounds__(256) void gemm_kernel(
    const float* __restrict__ Aq, const float* __restrict__ Ak,
    const float* __restrict__ Av, const bf16_t* __restrict__ Actx,
    const bf16_t* __restrict__ WT,
    bf16_t* __restrict__ oq, bf16_t* __restrict__ ok, bf16_t* __restrict__ ovT,
    float* __restrict__ otmp, int mode_base)
{
    int mode = mode_base + blockIdx.z;
    const float* Af = (mode == 0) ? Aq : (mode == 1) ? Ak : Av;
    const bf16_t* Wp = WT + ((size_t)mode << 20);
    // A f32 [128 rows][16 chunks of 16B] = 32KB  |  B bf16 [128 rows][8 chunks] = 16KB
    __shared__ __align__(16) unsigned char sm[49152];
    int m0 = blockIdx.y * 128, n0 = blockIdx.x * 128;
    int t = threadIdx.x, wv = t >> 6, lane = t & 63, lrow = lane & 15, g = lane >> 4;
    int wm = (wv >> 1) * 64, wn = (wv & 1) * 64;
    f32x4 acc[4][4] = {};
    for (int kt = 0; kt < 16; ++kt) {
        int k0 = kt * 64;
        __syncthreads();
        if (mode < 3) {
#pragma unroll
            for (int j = 0; j < 8; ++j) {
                int ci = j * 256 + t;
                int row = ci >> 4, c = ci & 15;
                gl_lds16(Af + (size_t)(m0 + row) * 1024 + k0 + ((c ^ (row & 15)) << 2),
                         sm + j * 4096 + wv * 1024);
            }
        } else {
#pragma unroll
            for (int j = 0; j < 4; ++j) {
                int ci = j * 256 + t;
                int row = ci >> 3, c = ci & 7;
                gl_lds16(Actx + (size_t)(m0 + row) * 1024 + k0 + ((c ^ (row & 7)) << 3),
                         sm + j * 4096 + wv * 1024);
            }
        }
#pragma unroll
        for (int j = 0; j < 4; ++j) {
            int ci = j * 256 + t;
            int row = ci >> 3, c = ci & 7;
            gl_lds16(Wp + (size_t)(n0 + row) * 1024 + k0 + ((c ^ (row & 7)) << 3),
                     sm + 32768 + j * 4096 + wv * 1024);
        }
        __syncthreads();
#pragma unroll
        for (int win = 0; win < 2; ++win) {
            bf16x8 av[4], bv[4];
#pragma unroll
            for (int i = 0; i < 4; ++i) {
                int ra = wm + i * 16 + lrow;
                if (mode < 3) {
                    int c0 = win * 8 + g * 2;
                    f32x4 lo = *(const f32x4*)(sm + ra * 256 + (((c0) ^ (ra & 15)) * 16));
                    f32x4 hi = *(const f32x4*)(sm + ra * 256 + (((c0 + 1) ^ (ra & 15)) * 16));
                    bf16x8 fa = {f2b(lo[0]), f2b(lo[1]), f2b(lo[2]), f2b(lo[3]),
                                 f2b(hi[0]), f2b(hi[1]), f2b(hi[2]), f2b(hi[3])};
                    av[i] = fa;
                } else {
                    int c = win * 4 + g;
                    av[i] = *(const bf16x8*)(sm + ra * 128 + ((c ^ (ra & 7)) * 16));
                }
                int rb = wn + i * 16 + lrow;
                int cb = win * 4 + g;
                bv[i] = *(const bf16x8*)(sm + 32768 + rb * 128 + ((cb ^ (rb & 7)) * 16));
            }
#pragma unroll
            for (int i = 0; i < 4; ++i)
#pragma unroll
                for (int j2 = 0; j2 < 4; ++j2)
                    acc[i][j2] = MFMA16(av[i], bv[j2], acc[i][j2]);
        }
    }
    // epilogue: D frag layout col = lane&15, row = 4*(lane>>4)+reg
#pragma unroll
    for (int i = 0; i < 4; ++i)
#pragma unroll
        for (int j = 0; j < 4; ++j)
#pragma unroll
            for (int r = 0; r < 4; ++r) {
                int m = m0 + wm + i * 16 + 4 * g + r;
                int n = n0 + wn + j * 16 + lrow;
                float vv = acc[i][j][r];
                if (mode == 3) {
                    otmp[(size_t)m * 1024 + n] = vv;
                } else {
                    int b = m >> 10, l = m & 1023, h = n >> 6, d = n & 63;
                    int bh = (b << 4) | h;
                    if (mode == 0)
                        oq[((size_t)bh * 1024 + l) * 64 + d] = f2b(vv);
                    else if (mode == 1)
                        ok[((size_t)bh * 1024 + l) * 64 + d] = f2b(vv);
                    else
                        ovT[(size_t)bh * 65536 + (size_t)(l >> 5) * 2048 + d * 32 + (l & 31)] = f2b(vv);
                }
            }
}

// ---------------------------------------------------------------------------
// attn: per (qt, bh): 8 waves x 16 q-rows. No K LDS (B-frags direct from L2).
// Mask converted once to a bitmask in LDS. No barriers in the main loops
// (P tile is per-wave; DS ops are in-order per wave).
// Pass 1: denom = sum(exp(s/8)); pass 2: write attn f32 + ctx via P@V MFMA.
// ---------------------------------------------------------------------------
__global__ __launch_bounds__(512) void attn_kernel(
    const bf16_t* __restrict__ wq, const bf16_t* __restrict__ wk,
    const bf16_t* __restrict__ wvT, const int* __restrict__ mask,
    float* __restrict__ attn, bf16_t* __restrict__ ctxo)
{
    __shared__ __align__(16) unsigned char sm[24576];  // mbits 16KB | P 8x1KB @16384
    unsigned* mbits = (unsigned*)sm;
    int qt = blockIdx.x, bh = blockIdx.y;
    int b = bh >> 4, h = bh & 15;
    int t = threadIdx.x, wv = t >> 6, lane = t & 63, lrow = lane & 15, g = lane >> 4;
    // build mask bitmask: word wi = qr*32 + w covers ints [wi*32, wi*32+32)
    {
        const int4* mp = (const int4*)(mask + ((size_t)b << 20) + (size_t)qt * 128 * 1024);
#pragma unroll
        for (int it = 0; it < 8; ++it) {
            int wi = it * 512 + t;
            const int4* p = mp + wi * 8;
            unsigned bits = 0;
#pragma unroll
            for (int c2 = 0; c2 < 8; ++c2) {
                int4 mv = p[c2];
                bits |= (mv.x != 0 ? 1u : 0u) << (c2 * 4);
                bits |= (mv.y != 0 ? 1u : 0u) << (c2 * 4 + 1);
                bits |= (mv.z != 0 ? 1u : 0u) << (c2 * 4 + 2);
                bits |= (mv.w != 0 ? 1u : 0u) << (c2 * 4 + 3);
            }
            mbits[wi] = bits;
        }
    }
    __syncthreads();
    int q0 = qt * 128 + wv * 16;
    const bf16_t* Qb = wq + ((size_t)bh * 1024 + q0 + lrow) * 64;
    bf16x8 aq0 = *(const bf16x8*)(Qb + 8 * g);
    bf16x8 aq1 = *(const bf16x8*)(Qb + 32 + 8 * g);
    const bf16_t* Kb = wk + (size_t)bh * 65536;
    const unsigned* mrow = mbits + (wv * 16 + 4 * g) * 32;  // rows 4g..4g+3 of this wave
    f32x4 zf = {0.f, 0.f, 0.f, 0.f};
    float denom[4] = {0.f, 0.f, 0.f, 0.f};
    // ---- pass 1: k in pairs of 16 (one mbits word per (r, pair)) ----
    for (int kp = 0; kp < 32; ++kp) {
        int kcA = kp * 32 + lrow;
        bf16x8 k0a = *(const bf16x8*)(Kb + (size_t)kcA * 64 + 8 * g);
        bf16x8 k1a = *(const bf16x8*)(Kb + (size_t)kcA * 64 + 32 + 8 * g);
        bf16x8 k0b = *(const bf16x8*)(Kb + (size_t)(kcA + 16) * 64 + 8 * g);
        bf16x8 k1b = *(const bf16x8*)(Kb + (size_t)(kcA + 16) * 64 + 32 + 8 * g);
        f32x4 sA = MFMA16(aq0, k0a, zf);
        sA = MFMA16(aq1, k1a, sA);
        f32x4 sB = MFMA16(aq0, k0b, zf);
        sB = MFMA16(aq1, k1b, sB);
#pragma unroll
        for (int r = 0; r < 4; ++r) {
            unsigned w = mrow[r * 32 + kp];
            float mA = ((w >> lrow) & 1u) ? 1.f : 0.f;
            float mB = ((w >> (16 + lrow)) & 1u) ? 1.f : 0.f;
            denom[r] += mA * __expf(0.125f * sA[r]) + mB * __expf(0.125f * sB[r]);
        }
    }
#pragma unroll
    for (int r = 0; r < 4; ++r) {
        float e = denom[r];
        e += __shfl_xor(e, 1);
        e += __shfl_xor(e, 2);
        e += __shfl_xor(e, 4);
        e += __shfl_xor(e, 8);
        denom[r] = e;
    }
    float inv[4];
#pragma unroll
    for (int r = 0; r < 4; ++r) inv[r] = denom[r] > 0.f ? 1.f / denom[r] : 0.f;
    // ---- pass 2 ----
    float* Ao = attn + ((size_t)bh * 1024 + q0) * 1024;
    const bf16_t* Vb = wvT + (size_t)bh * 65536;
    unsigned pb = 16384 + wv * 1024;  // per-wave P tile 16x32 bf16
    f32x4 cacc[4] = {};
    for (int k2 = 0; k2 < 32; ++k2) {
        int kcA = k2 * 32 + lrow;
        bf16x8 k0a = *(const bf16x8*)(Kb + (size_t)kcA * 64 + 8 * g);
        bf16x8 k1a = *(const bf16x8*)(Kb + (size_t)kcA * 64 + 32 + 8 * g);
        bf16x8 k0b = *(const bf16x8*)(Kb + (size_t)(kcA + 16) * 64 + 8 * g);
        bf16x8 k1b = *(const bf16x8*)(Kb + (size_t)(kcA + 16) * 64 + 32 + 8 * g);
        f32x4 sA = MFMA16(aq0, k0a, zf);
        sA = MFMA16(aq1, k1a, sA);
        f32x4 sB = MFMA16(aq0, k0b, zf);
        sB = MFMA16(aq1, k1b, sB);
#pragma unroll
        for (int r = 0; r < 4; ++r) {
            int qr = 4 * g + r;
            unsigned w = mrow[r * 32 + k2];
            float mA = ((w >> lrow) & 1u) ? inv[r] : 0.f;
            float mB = ((w >> (16 + lrow)) & 1u) ? inv[r] : 0.f;
            float pA = __expf(0.125f * sA[r]) * mA;
            float pB = __expf(0.125f * sB[r]) * mB;
            Ao[(size_t)qr * 1024 + kcA] = pA;
            Ao[(size_t)qr * 1024 + kcA + 16] = pB;
            unsigned chA = (unsigned)((lrow >> 3) ^ (qr & 3));
            unsigned chB = (unsigned)((2 + (lrow >> 3)) ^ (qr & 3));
            *(bf16_t*)(sm + pb + qr * 64 + chA * 16 + (lrow & 7) * 2) = f2b(pA);
            *(bf16_t*)(sm + pb + qr * 64 + chB * 16 + (lrow & 7) * 2) = f2b(pB);
        }
        // per-wave DS in-order: write->read of own P tile needs no barrier
        bf16x8 ap = *(const bf16x8*)(sm + pb + lrow * 64 + ((g ^ (lrow & 3)) * 16));
#pragma unroll
        for (int dt = 0; dt < 4; ++dt) {
            bf16x8 bvv = *(const bf16x8*)(Vb + (size_t)k2 * 2048 + (dt * 16 + lrow) * 32 + 8 * g);
            cacc[dt] = MFMA16(ap, bvv, cacc[dt]);
        }
    }
    bf16_t* Co = ctxo + ((size_t)b * 1024 + q0) * 1024 + h * 64;
#pragma unroll
    for (int dt = 0; dt < 4; ++dt)
#pragma unroll
        for (int r = 0; r < 4; ++r)
            Co[(size_t)(4 * g + r) * 1024 + dt * 16 + lrow] = f2b(cacc[dt][r]);
}

// ---------------------------------------------------------------------------
// ln: out = LN(tmp + resid) * gamma + beta
// ---------------------------------------------------------------------------
__global__ __launch_bounds__(256) void ln_kernel(
    const float* __restrict__ tmp, const float* __restrict__ resid,
    const float* __restrict__ gamma, const float* __restrict__ beta,
    float* __restrict__ out)
{
    int row = blockIdx.x, t = threadIdx.x;
    const float4 x = *(const float4*)(tmp + (size_t)row * 1024 + t * 4);
    const float4 rs = *(const float4*)(resid + (size_t)row * 1024 + t * 4);
    float v0 = x.x + rs.x, v1 = x.y + rs.y, v2 = x.z + rs.z, v3 = x.w + rs.w;
    float s = v0 + v1 + v2 + v3;
    float q = v0 * v0 + v1 * v1 + v2 * v2 + v3 * v3;
#pragma unroll
    for (int m = 1; m < 64; m <<= 1) {
        s += __shfl_xor(s, m);
        q += __shfl_xor(q, m);
    }
    __shared__ float ps[4], pq[4];
    int wv = t >> 6;
    if ((t & 63) == 0) { ps[wv] = s; pq[wv] = q; }
    __syncthreads();
    s = ps[0] + ps[1] + ps[2] + ps[3];
    q = pq[0] + pq[1] + pq[2] + pq[3];
    float mean = s * (1.f / 1024.f);
    float var = q * (1.f / 1024.f) - mean * mean;
    float rstd = rsqrtf(var + 1e-6f);
    const float4 gm = *(const float4*)(gamma + t * 4);
    const float4 bt = *(const float4*)(beta + t * 4);
    float4 o;
    o.x = (v0 - mean) * rstd * gm.x + bt.x;
    o.y = (v1 - mean) * rstd * gm.y + bt.y;
    o.z = (v2 - mean) * rstd * gm.z + bt.z;
    o.w = (v3 - mean) * rstd * gm.w + bt.w;
    *(float4*)(out + (size_t)row * 1024 + t * 4) = o;
}

extern "C" void kernel_launch(void* const* d_in, const int* in_sizes, int n_in,
                              void* d_out, int out_size, void* d_ws, size_t ws_size,
                              hipStream_t stream) {
    const float* q = (const float*)d_in[0];
    const float* k = (const float*)d_in[1];
    const float* v = (const float*)d_in[2];
    const int* mask = (const int*)d_in[3];
    const float* w_q = (const float*)d_in[4];
    const float* w_k = (const float*)d_in[5];
    const float* w_v = (const float*)d_in[6];
    const float* w_o = (const float*)d_in[7];
    const float* gamma = (const float*)d_in[8];
    const float* beta = (const float*)d_in[9];
    float* out = (float*)d_out;
    float* attn = out + (size_t)8 * 1024 * 1024;

    unsigned char* ws = (unsigned char*)d_ws;
    bf16_t* ws_q = (bf16_t*)(ws);                    // 16 MB  [bh][l][64]
    bf16_t* ws_k = (bf16_t*)(ws + 16777216);         // 16 MB  [bh][l][64]
    bf16_t* ws_vT = (bf16_t*)(ws + 33554432);        // 16 MB  [bh][k>>5][d][k&31]
    bf16_t* ws_ctx = (bf16_t*)(ws + 50331648);       // 16 MB  [b*l][h*64+d]
    bf16_t* WT = (bf16_t*)(ws + 67108864);           // 8 MB   WTq,WTk,WTv,WTo
    float* tmp = (float*)(ws);                       // 32 MB, overlays dead ws_q/ws_k

    prep_kernel<<<dim3(16, 16, 4), 256, 0, stream>>>(w_q, w_k, w_v, w_o, WT);
    gemm_kernel<<<dim3(8, 64, 3), 256, 0, stream>>>(q, k, v, nullptr, WT,
                                                    ws_q, ws_k, ws_vT, nullptr, 0);
    attn_kernel<<<dim3(8, 128), 512, 0, stream>>>(ws_q, ws_k, ws_vT, mask, attn, ws_ctx);
    gemm_kernel<<<dim3(8, 64, 1), 256, 0, stream>>>(nullptr, nullptr, nullptr, ws_ctx, WT,
                                                    nullptr, nullptr, nullptr, tmp, 3);
    ln_kernel<<<8192, 256, 0, stream>>>(tmp, q, gamma, beta, out);
}